// Round 1
// baseline (258.678 us; speedup 1.0000x reference)
//
#include <hip/hip_runtime.h>
#include <cstdint>
#include <cstddef>

#define RHO 1e-8f
#define EPSV 1e-8f

__device__ __forceinline__ float wave_sum(float v) {
#pragma unroll
  for (int off = 1; off < 64; off <<= 1) v += __shfl_xor(v, off, 64);
  return v;
}

__device__ __forceinline__ float wave_max(float v) {
#pragma unroll
  for (int off = 1; off < 64; off <<= 1) v = fmaxf(v, __shfl_xor(v, off, 64));
  return v;
}

// ---------------- Stage 1: outer_forward -> (maxval, argmax) per (b, field) ----
// grid 1024 x 256: 4 fields per block, one wave per field, lane = mem row.
__global__ __launch_bounds__(256) void stage1_kernel(
    const float* __restrict__ xs, const float* __restrict__ mm0,
    float* __restrict__ maxv1, int* __restrict__ idx1) {
  const int lane = threadIdx.x & 63;
  const int wave = threadIdx.x >> 6;
  const int f = blockIdx.x * 4 + wave;

  // load my memory row (mem = lane), shifted by -0.5, into registers
  const float* mrow = mm0 + ((size_t)f * 64 + lane) * 64;
  float m[64];
#pragma unroll
  for (int j = 0; j < 16; ++j) {
    float4 v = reinterpret_cast<const float4*>(mrow)[j];
    m[4 * j + 0] = v.x - 0.5f;
    m[4 * j + 1] = v.y - 0.5f;
    m[4 * j + 2] = v.z - 0.5f;
    m[4 * j + 3] = v.w - 0.5f;
  }
  float mn = 0.f;
#pragma unroll
  for (int d = 0; d < 64; ++d) mn = fmaf(m[d], m[d], mn);
  mn = sqrtf(mn);

  for (int b = 0; b < 32; ++b) {
    // lane d loads x[b,f,d]; shift once per lane
    float xv = xs[((size_t)b * 4096 + f) * 64 + lane] - 0.5f;
    float xn = sqrtf(wave_sum(xv * xv));
    float acc = 0.f;
#pragma unroll
    for (int d = 0; d < 64; ++d) {
      float xd = __int_as_float(__builtin_amdgcn_readlane(__float_as_int(xv), d));
      acc = fmaf(m[d], xd, acc);
    }
    float val = (acc * 0.5f) / (mn * xn + RHO) + 0.5f;
    float mx = wave_max(val);
    unsigned long long t = __ballot(val == mx);
    int j = __ffsll((long long)t) - 1;  // first (lowest) index on ties == jnp.argmax
    if (lane == 0) {
      maxv1[b * 4096 + f] = mx;
      idx1[b * 4096 + f] = j;
    }
  }
}

// ---------------- Stage 2/3: hidden_forward ----------------------------------
// prop[h] = sum_c mm[n,c,h,k(b,c)] * v(b,c);  out = prop / (8*||v|| + rho)
// LDS layout tile[c_local][h][k] with k-stride 65 -> conflict-free column gather.
template <int NFIN, int BG, bool FULL>
__global__ __launch_bounds__(256) void hidden_kernel(
    const float* __restrict__ maxv_in, const int* __restrict__ idx_in,
    const float* __restrict__ mm,
    float* __restrict__ maxv_out, int* __restrict__ idx_out,
    float* __restrict__ hfull, int* __restrict__ trig) {
  constexpr int NODES = NFIN / 8;
  constexpr int GROUPS = 32 / BG;  // workgroups per node
  constexpr int BPW = BG / 4;      // batches per wave
  const int node = blockIdx.x / GROUPS;
  const int bg = blockIdx.x % GROUPS;
  const int lane = threadIdx.x & 63;
  const int wave = threadIdx.x >> 6;
  const int b0 = bg * BG + wave * BPW;

  __shared__ float tile[2 * 64 * 65];  // 33280 B
  const float* mmn = mm + (size_t)node * 8 * 64 * 64;

  float acc[BPW];
#pragma unroll
  for (int i = 0; i < BPW; ++i) acc[i] = 0.f;

  for (int pass = 0; pass < 4; ++pass) {
    __syncthreads();
    // stage children c = 2*pass, 2*pass+1 (2*64*64 floats = 2048 float4)
#pragma unroll
    for (int i = 0; i < 8; ++i) {
      int t4 = threadIdx.x + i * 256;  // [0, 2048)
      int cl = t4 >> 10;               // 1024 float4 per child
      int rem = t4 & 1023;             // over [h][kq]
      int h = rem >> 4;
      int kq = rem & 15;
      float4 v = reinterpret_cast<const float4*>(mmn + (size_t)(pass * 2 + cl) * 4096)[rem];
      float* dst = &tile[(cl * 64 + h) * 65 + kq * 4];
      dst[0] = v.x;
      dst[1] = v.y;
      dst[2] = v.z;
      dst[3] = v.w;
    }
    __syncthreads();
#pragma unroll
    for (int i = 0; i < BPW; ++i) {
      int b = b0 + i;
#pragma unroll
      for (int cl = 0; cl < 2; ++cl) {
        int c = pass * 2 + cl;
        int k = idx_in[(size_t)b * NFIN + node * 8 + c];
        float v = maxv_in[(size_t)b * NFIN + node * 8 + c];
        acc[i] = fmaf(tile[(cl * 64 + lane) * 65 + k], v, acc[i]);
      }
    }
  }

#pragma unroll
  for (int i = 0; i < BPW; ++i) {
    int b = b0 + i;
    float s2 = 0.f;
#pragma unroll
    for (int c = 0; c < 8; ++c) {
      float v = maxv_in[(size_t)b * NFIN + node * 8 + c];
      s2 = fmaf(v, v, s2);
    }
    float denom = 8.f * sqrtf(s2) + RHO;
    float val = acc[i] / denom;  // lane = h
    float mxv = wave_max(val);
    unsigned long long tb = __ballot(val == mxv);
    int j = __ffsll((long long)tb) - 1;
    if constexpr (FULL) {
      hfull[((size_t)b * NODES + node) * 64 + lane] = val;
      unsigned long long big = __ballot(val > 0.9f);
      if (lane == 0) {
        maxv_out[b * NODES + node] = mxv;
        idx_out[b * NODES + node] = j;
        trig[b * NODES + node] = (big == 0ULL) ? 1 : 0;  // no entry > 0.9
      }
    } else {
      if (lane == 0) {
        maxv_out[b * NODES + node] = mxv;
        idx_out[b * NODES + node] = j;
      }
    }
  }
}

// ---------------- Stage 4: growth_argmaxi ------------------------------------
// one wave per node n
__global__ __launch_bounds__(64) void growth_kernel(
    const float* __restrict__ counts, const float* __restrict__ h2,
    const float* __restrict__ maxv3, const int* __restrict__ idx3,
    const int* __restrict__ trig3, float* __restrict__ out) {
  const int n = blockIdx.x;
  const int lane = threadIdx.x;  // 0..63
  __shared__ float cnt[64];
  __shared__ int sidx[64];
  __shared__ int flagged[64];
  __shared__ int comp[64];
  __shared__ int finals[32];
  __shared__ int keptcnt;

  cnt[lane] = counts[n * 64 + lane];
  flagged[lane] = 0;
  __syncthreads();

  // stable ascending argsort of counts[n] (rank = stable rank)
  float cl = cnt[lane];
  int rank = 0;
  for (int j = 0; j < 64; ++j) {
    float cj = cnt[j];
    rank += (cj < cl || (cj == cl && j < lane)) ? 1 : 0;
  }
  sidx[rank] = lane;
  __syncthreads();

  // reserved marks from non-triggered batches (res = argsort(normal)[-1])
  if (lane < 32) {
    int b = lane;
    if (!trig3[b * 64 + n]) {
      int j = idx3[b * 64 + n];
      float a = fabsf(maxv3[b * 64 + n]);
      int res;
      if (a > EPSV) res = j;                 // normal[j] = a/(a-eps) > 0: unique max
      else if (a == 0.f) res = 63;           // all-zero row: stable argsort last = 63
      else if (a == EPSV) res = j;           // a/(a-eps) = +inf
      else res = (j == 63) ? 62 : 63;        // single negative entry: last zero wins
      flagged[res] = 1;
    }
  }
  __syncthreads();

  // move MARK to back (stable compaction of non-reserved sorted indices)
  int s = sidx[lane];
  int keep = flagged[s] ? 0 : 1;
  unsigned long long kb = __ballot(keep);
  int pos = __popcll(kb & ((1ULL << lane) - 1ULL));
  if (keep) comp[pos] = s;
  if (lane == 0) keptcnt = __popcll(kb);
  __syncthreads();

  if (lane < 32) finals[lane] = (lane < keptcnt) ? comp[lane] : sidx[lane];
  __syncthreads();

  for (int b = 0; b < 32; ++b) {
    int tg = trig3[b * 64 + n];
    int idxb;
    float a;
    if (tg) {
      idxb = finals[b];
      float val = h2[((size_t)b * 64 + n) * 64 + idxb];
      if (val == 0.f) val = 1.f;
      a = fabsf(val);
    } else {
      idxb = idx3[b * 64 + n];
      a = fabsf(maxv3[b * 64 + n]);
    }
    float v = a / (a - EPSV);
    out[((size_t)b * 64 + n) * 64 + lane] = (lane == idxb) ? v : 0.f;
  }
}

extern "C" void kernel_launch(void* const* d_in, const int* in_sizes, int n_in,
                              void* d_out, int out_size, void* d_ws, size_t ws_size,
                              hipStream_t stream) {
  const float* xs = (const float*)d_in[0];      // (32, 4096, 64)
  const float* mm0 = (const float*)d_in[1];     // (4096, 64, 64)
  const float* mm1 = (const float*)d_in[2];     // (512, 8, 64, 64)
  const float* mm2 = (const float*)d_in[3];     // (64, 8, 64, 64)
  const float* counts = (const float*)d_in[4];  // (64, 64)
  float* out = (float*)d_out;                   // (32, 64, 64)
  char* ws = (char*)d_ws;

  float* maxv1 = (float*)(ws + 0);        // 32*4096 f32
  int* idx1 = (int*)(ws + 524288);        // 32*4096 i32
  float* maxv2 = (float*)(ws + 1048576);  // 32*512 f32
  int* idx2 = (int*)(ws + 1114112);       // 32*512 i32
  float* h2 = (float*)(ws + 1179648);     // 32*64*64 f32
  float* maxv3 = (float*)(ws + 1703936);  // 32*64 f32
  int* idx3 = (int*)(ws + 1712128);       // 32*64 i32
  int* trig3 = (int*)(ws + 1720320);      // 32*64 i32

  stage1_kernel<<<dim3(1024), dim3(256), 0, stream>>>(xs, mm0, maxv1, idx1);
  hidden_kernel<4096, 32, false><<<dim3(512), dim3(256), 0, stream>>>(
      maxv1, idx1, mm1, maxv2, idx2, (float*)nullptr, (int*)nullptr);
  hidden_kernel<512, 8, true><<<dim3(256), dim3(256), 0, stream>>>(
      maxv2, idx2, mm2, maxv3, idx3, h2, trig3);
  growth_kernel<<<dim3(64), dim3(64), 0, stream>>>(counts, h2, maxv3, idx3, trig3, out);
}